// Round 1
// baseline (501.357 us; speedup 1.0000x reference)
//
#include <hip/hip_runtime.h>

// Problem constants
#define BATCH   1024
#define FDIM    2048
#define LDIM    80
#define EDIM    512
#define ODIM    2048
#define NEXP    8
#define INDIM   2560   // FDIM + EDIM

typedef __bf16 bf16x8 __attribute__((ext_vector_type(8)));
typedef float  f32x4  __attribute__((ext_vector_type(4)));

__device__ __forceinline__ unsigned short f2bf(float x) {
    // round-to-nearest-even fp32 -> bf16
    unsigned int u = __float_as_uint(x);
    u += 0x7fffu + ((u >> 16) & 1u);
    return (unsigned short)(u >> 16);
}
__device__ __forceinline__ unsigned int pack2(float lo, float hi) {
    return (unsigned int)f2bf(lo) | ((unsigned int)f2bf(hi) << 16);
}
__device__ __forceinline__ float bf2f(unsigned short h) {
    return __uint_as_float((unsigned int)h << 16);
}
__device__ __forceinline__ void gload_lds16(const void* g, void* l) {
    // async global->LDS, 16B per lane; LDS dest = wave-uniform base + lane*16
    __builtin_amdgcn_global_load_lds(
        (__attribute__((address_space(1))) void*)g,
        (__attribute__((address_space(3))) void*)l,
        16, 0, 0);
}

// ---------------------------------------------------------------------------
// Kernel 1: combined = [features | labels @ label_embed] as bf16, row-major
// 256 blocks, each handles 4 batch rows, 256 threads.
// ---------------------------------------------------------------------------
__global__ __launch_bounds__(256) void prep_kernel(
    const float* __restrict__ features, const float* __restrict__ labels,
    const float* __restrict__ label_embed, unsigned short* __restrict__ cb)
{
    const int b0 = blockIdx.x * 4;
    const int t  = threadIdx.x;
    __shared__ float lab[4][LDIM];
    for (int idx = t; idx < 4 * LDIM; idx += 256) {
        lab[idx / LDIM][idx % LDIM] = labels[(size_t)(b0 + idx / LDIM) * LDIM + (idx % LDIM)];
    }
    __syncthreads();

    // features -> bf16 copy: thread t does row r=t>>6, cols (t&63)*4 within 8 chunks
    {
        const int r = t >> 6, c64 = t & 63;
        const float4* F4 = (const float4*)features;
        #pragma unroll
        for (int ch = 0; ch < 8; ++ch) {
            float4 v = F4[(size_t)(b0 + r) * (FDIM / 4) + c64 + 64 * ch];
            uint2 pk;
            pk.x = pack2(v.x, v.y);
            pk.y = pack2(v.z, v.w);
            *(uint2*)(cb + (size_t)(b0 + r) * INDIM + (size_t)(c64 + 64 * ch) * 4) = pk;
        }
    }
    // label embedding: thread t handles cols 2*t, 2*t+1 for all 4 rows
    {
        const int j = 2 * t;
        float acc[4][2] = {{0,0},{0,0},{0,0},{0,0}};
        const float2* le2 = (const float2*)label_embed;
        for (int l = 0; l < LDIM; ++l) {
            float2 le = le2[(size_t)l * (EDIM / 2) + t];
            #pragma unroll
            for (int r = 0; r < 4; ++r) {
                float lv = lab[r][l];
                acc[r][0] += lv * le.x;
                acc[r][1] += lv * le.y;
            }
        }
        #pragma unroll
        for (int r = 0; r < 4; ++r) {
            *(unsigned int*)(cb + (size_t)(b0 + r) * INDIM + FDIM + j) = pack2(acc[r][0], acc[r][1]);
        }
    }
}

// ---------------------------------------------------------------------------
// Kernel 2: gating = sigmoid(combined @ gate_w + gate_b). 1 block per row.
// ---------------------------------------------------------------------------
__global__ __launch_bounds__(256) void gate_kernel(
    const unsigned short* __restrict__ cb, const float* __restrict__ gw,
    const float* __restrict__ gb, float* __restrict__ gating)
{
    const int b = blockIdx.x, t = threadIdx.x;
    float p[NEXP] = {0,0,0,0,0,0,0,0};
    for (int i = t; i < INDIM; i += 256) {
        float c = bf2f(cb[(size_t)b * INDIM + i]);
        const float4* g4 = (const float4*)(gw + (size_t)i * NEXP);
        float4 u = g4[0], v = g4[1];
        p[0] += c * u.x; p[1] += c * u.y; p[2] += c * u.z; p[3] += c * u.w;
        p[4] += c * v.x; p[5] += c * v.y; p[6] += c * v.z; p[7] += c * v.w;
    }
    __shared__ float red[4][NEXP];
    const int lane = t & 63, wave = t >> 6;
    #pragma unroll
    for (int e = 0; e < NEXP; ++e) {
        float v = p[e];
        v += __shfl_down(v, 32); v += __shfl_down(v, 16); v += __shfl_down(v, 8);
        v += __shfl_down(v, 4);  v += __shfl_down(v, 2);  v += __shfl_down(v, 1);
        if (lane == 0) red[wave][e] = v;
    }
    __syncthreads();
    if (t < NEXP) {
        float s = red[0][t] + red[1][t] + red[2][t] + red[3][t] + gb[t];
        gating[(size_t)b * NEXP + t] = 1.0f / (1.0f + __expf(-s));
    }
}

// ---------------------------------------------------------------------------
// Kernel 3: main MoE GEMM.
// grid (16 o-tiles, 8 b-tiles, 8 experts), 256 threads (4 waves).
// Tile 128x128, BK=32, mfma_f32_16x16x32_bf16, wave = 64x64 (4x4 frags).
// A (combined bf16) staged via global_load_lds; W (fp32) staged with on-the-fly
// bf16 convert into [n][k]-transposed LDS. Epilogue: gate-scale + gated bias,
// atomic accumulate over experts into out.
// ---------------------------------------------------------------------------
__global__ __launch_bounds__(256) void moe_gemm(
    const unsigned short* __restrict__ cb, const float* __restrict__ W,
    const float* __restrict__ gating, const float* __restrict__ eb,
    float* __restrict__ out)
{
    __shared__ unsigned short As[128 * 32];  // [m][k], 64B rows
    __shared__ unsigned short Bs[128 * 32];  // [n][k], 64B rows (transposed W tile)

    const int t = threadIdx.x;
    const int lane = t & 63, wave = t >> 6;
    const int n0 = blockIdx.x * 128;
    const int m0 = blockIdx.y * 128;
    const int e  = blockIdx.z;

    f32x4 acc[4][4];
    #pragma unroll
    for (int i = 0; i < 4; ++i)
        #pragma unroll
        for (int j = 0; j < 4; ++j) acc[i][j] = (f32x4){0.f, 0.f, 0.f, 0.f};

    // A staging: row = t>>2 (per 64-row issue), 16B chunk = t&3
    const int arow = t >> 2, acg = t & 3;
    const unsigned short* ag0 = cb + (size_t)(m0 + arow) * INDIM + acg * 8;
    unsigned short* al0 = As + wave * 512;           // bytes: wave*1024
    unsigned short* al1 = As + 2048 + wave * 512;    // + 4096 B (rows 64..127)

    // B staging: k-pair = t&15 (k = 2*(t&15), 2*(t&15)+1), o-chunk = (t>>4)*8
    const int bg = t & 15;
    const int bu = t >> 4;
    const float* wg = W + (size_t)e * ((size_t)INDIM * ODIM) + (size_t)(2 * bg) * ODIM + n0 + bu * 8;
    unsigned int* bl = (unsigned int*)Bs + bg + bu * 128;  // dword [o][kpair]

    const int fm = lane & 15, fq = lane >> 4;
    const int wn = (wave & 1) * 64;   // wave n-offset
    const int wm = (wave >> 1) * 64;  // wave m-offset

    for (int k0 = 0; k0 < INDIM; k0 += 32) {
        __syncthreads();
        // A tile: 2 async 16B issues per thread
        gload_lds16(ag0 + k0, al0);
        gload_lds16(ag0 + (size_t)64 * INDIM + k0, al1);
        // B tile: 2 k-rows x 8 o, fp32 -> packed bf16 k-pairs, transposed store
        const float* wp = wg + (size_t)k0 * ODIM;
        float4 r0a = *(const float4*)(wp);
        float4 r0b = *(const float4*)(wp + 4);
        float4 r1a = *(const float4*)(wp + ODIM);
        float4 r1b = *(const float4*)(wp + ODIM + 4);
        bl[0 * 16] = pack2(r0a.x, r1a.x);
        bl[1 * 16] = pack2(r0a.y, r1a.y);
        bl[2 * 16] = pack2(r0a.z, r1a.z);
        bl[3 * 16] = pack2(r0a.w, r1a.w);
        bl[4 * 16] = pack2(r0b.x, r1b.x);
        bl[5 * 16] = pack2(r0b.y, r1b.y);
        bl[6 * 16] = pack2(r0b.z, r1b.z);
        bl[7 * 16] = pack2(r0b.w, r1b.w);
        __syncthreads();

        bf16x8 af[4], bfr[4];
        #pragma unroll
        for (int mi = 0; mi < 4; ++mi)
            af[mi] = *(const bf16x8*)(As + (wm + mi * 16 + fm) * 32 + fq * 8);
        #pragma unroll
        for (int ni = 0; ni < 4; ++ni)
            bfr[ni] = *(const bf16x8*)(Bs + (wn + ni * 16 + fm) * 32 + fq * 8);
        #pragma unroll
        for (int mi = 0; mi < 4; ++mi)
            #pragma unroll
            for (int ni = 0; ni < 4; ++ni)
                acc[mi][ni] = __builtin_amdgcn_mfma_f32_16x16x32_bf16(af[mi], bfr[ni], acc[mi][ni], 0, 0, 0);
    }

    // Epilogue: out[b,o] += g[b,e] * (acc + expert_b[e,o])
    #pragma unroll
    for (int mi = 0; mi < 4; ++mi) {
        const int grow = m0 + wm + mi * 16 + fq * 4;  // C/D row = quad*4 + reg
        const float g0 = gating[(size_t)(grow + 0) * NEXP + e];
        const float g1 = gating[(size_t)(grow + 1) * NEXP + e];
        const float g2 = gating[(size_t)(grow + 2) * NEXP + e];
        const float g3 = gating[(size_t)(grow + 3) * NEXP + e];
        #pragma unroll
        for (int ni = 0; ni < 4; ++ni) {
            const int gcol = n0 + wn + ni * 16 + fm;  // C/D col = lane&15
            const float bias = eb[(size_t)e * ODIM + gcol];
            f32x4 a = acc[mi][ni];
            unsafeAtomicAdd(out + (size_t)(grow + 0) * ODIM + gcol, g0 * (a.x + bias));
            unsafeAtomicAdd(out + (size_t)(grow + 1) * ODIM + gcol, g1 * (a.y + bias));
            unsafeAtomicAdd(out + (size_t)(grow + 2) * ODIM + gcol, g2 * (a.z + bias));
            unsafeAtomicAdd(out + (size_t)(grow + 3) * ODIM + gcol, g3 * (a.w + bias));
        }
    }
}

// ---------------------------------------------------------------------------
extern "C" void kernel_launch(void* const* d_in, const int* in_sizes, int n_in,
                              void* d_out, int out_size, void* d_ws, size_t ws_size,
                              hipStream_t stream) {
    const float* features    = (const float*)d_in[0];
    const float* labels      = (const float*)d_in[1];
    const float* label_embed = (const float*)d_in[2];
    const float* gate_w      = (const float*)d_in[3];
    const float* gate_b      = (const float*)d_in[4];
    const float* expert_w    = (const float*)d_in[5];
    const float* expert_b    = (const float*)d_in[6];
    float* out = (float*)d_out;

    // ws layout: combined bf16 [1024][2560] (5,242,880 B) + gating f32 [1024][8]
    unsigned short* cb = (unsigned short*)d_ws;
    float* gating = (float*)((char*)d_ws + (size_t)BATCH * INDIM * 2);

    hipMemsetAsync(d_out, 0, (size_t)BATCH * ODIM * sizeof(float), stream);

    prep_kernel<<<BATCH / 4, 256, 0, stream>>>(features, labels, label_embed, cb);
    gate_kernel<<<BATCH, 256, 0, stream>>>(cb, gate_w, gate_b, gating);
    moe_gemm<<<dim3(ODIM / 128, BATCH / 128, NEXP), 256, 0, stream>>>(cb, expert_w, gating, expert_b, out);
}

// Round 2
// 458.574 us; speedup vs baseline: 1.0933x; 1.0933x over previous
//
#include <hip/hip_runtime.h>
#include <hip/hip_bf16.h>

// Problem constants
#define BATCH   1024
#define FDIM    2048
#define LDIM    80
#define EDIM    512
#define ODIM    2048
#define NEXP    8
#define INDIM   2560   // FDIM + EDIM

typedef __bf16 bf16x8 __attribute__((ext_vector_type(8)));
typedef float  f32x4  __attribute__((ext_vector_type(4)));

__device__ __forceinline__ unsigned int pack2(float lo, float hi) {
    // fp32x2 -> packed bf16x2 (RNE); should lower to v_cvt_pk_bf16_f32
    __hip_bfloat162 h = __float22bfloat162_rn(make_float2(lo, hi));
    unsigned int u;
    __builtin_memcpy(&u, &h, 4);
    return u;
}
__device__ __forceinline__ float bf2f(unsigned short h) {
    return __uint_as_float((unsigned int)h << 16);
}
__device__ __forceinline__ void gload_lds16(const void* g, void* l) {
    // async global->LDS, 16B per lane; LDS dest = wave-uniform base + lane*16
    __builtin_amdgcn_global_load_lds(
        (__attribute__((address_space(1))) void*)g,
        (__attribute__((address_space(3))) void*)l,
        16, 0, 0);
}

// ---------------------------------------------------------------------------
// Kernel 0 (fast path): W fp32 [e][k][o]  ->  Wb bf16 [e][o][k]
// grid (ODIM/256, INDIM/32, NEXP), 256 threads. Coalesced reads (1 KB/row),
// 64 B-per-lane sector-aligned scattered writes. Pure HBM-bound.
// ---------------------------------------------------------------------------
__global__ __launch_bounds__(256) void convert_w(
    const float* __restrict__ W, unsigned short* __restrict__ Wb)
{
    const int t  = threadIdx.x;
    const int o  = blockIdx.x * 256 + t;
    const int k0 = blockIdx.y * 32;
    const int e  = blockIdx.z;
    const float* src = W + (size_t)e * ((size_t)INDIM * ODIM) + (size_t)k0 * ODIM + o;
    unsigned int pk[16];
    #pragma unroll
    for (int j = 0; j < 16; ++j) {
        float a = src[(size_t)(2 * j) * ODIM];
        float b = src[(size_t)(2 * j + 1) * ODIM];
        pk[j] = pack2(a, b);
    }
    uint4* dst = (uint4*)(Wb + (size_t)e * ((size_t)ODIM * INDIM) + (size_t)o * INDIM + k0);
    dst[0] = make_uint4(pk[0],  pk[1],  pk[2],  pk[3]);
    dst[1] = make_uint4(pk[4],  pk[5],  pk[6],  pk[7]);
    dst[2] = make_uint4(pk[8],  pk[9],  pk[10], pk[11]);
    dst[3] = make_uint4(pk[12], pk[13], pk[14], pk[15]);
}

// ---------------------------------------------------------------------------
// Kernel 1: combined = [features | labels @ label_embed] as bf16, row-major
// ---------------------------------------------------------------------------
__global__ __launch_bounds__(256) void prep_kernel(
    const float* __restrict__ features, const float* __restrict__ labels,
    const float* __restrict__ label_embed, unsigned short* __restrict__ cb)
{
    const int b0 = blockIdx.x * 4;
    const int t  = threadIdx.x;
    __shared__ float lab[4][LDIM];
    for (int idx = t; idx < 4 * LDIM; idx += 256) {
        lab[idx / LDIM][idx % LDIM] = labels[(size_t)(b0 + idx / LDIM) * LDIM + (idx % LDIM)];
    }
    __syncthreads();

    {
        const int r = t >> 6, c64 = t & 63;
        const float4* F4 = (const float4*)features;
        #pragma unroll
        for (int ch = 0; ch < 8; ++ch) {
            float4 v = F4[(size_t)(b0 + r) * (FDIM / 4) + c64 + 64 * ch];
            uint2 pk;
            pk.x = pack2(v.x, v.y);
            pk.y = pack2(v.z, v.w);
            *(uint2*)(cb + (size_t)(b0 + r) * INDIM + (size_t)(c64 + 64 * ch) * 4) = pk;
        }
    }
    {
        const int j = 2 * t;
        float acc[4][2] = {{0,0},{0,0},{0,0},{0,0}};
        const float2* le2 = (const float2*)label_embed;
        for (int l = 0; l < LDIM; ++l) {
            float2 le = le2[(size_t)l * (EDIM / 2) + t];
            #pragma unroll
            for (int r = 0; r < 4; ++r) {
                float lv = lab[r][l];
                acc[r][0] += lv * le.x;
                acc[r][1] += lv * le.y;
            }
        }
        #pragma unroll
        for (int r = 0; r < 4; ++r) {
            *(unsigned int*)(cb + (size_t)(b0 + r) * INDIM + FDIM + j) = pack2(acc[r][0], acc[r][1]);
        }
    }
}

// ---------------------------------------------------------------------------
// Kernel 2: gating = sigmoid(combined @ gate_w + gate_b). 1 block per row.
// ---------------------------------------------------------------------------
__global__ __launch_bounds__(256) void gate_kernel(
    const unsigned short* __restrict__ cb, const float* __restrict__ gw,
    const float* __restrict__ gb, float* __restrict__ gating)
{
    const int b = blockIdx.x, t = threadIdx.x;
    float p[NEXP] = {0,0,0,0,0,0,0,0};
    for (int i = t; i < INDIM; i += 256) {
        float c = bf2f(cb[(size_t)b * INDIM + i]);
        const float4* g4 = (const float4*)(gw + (size_t)i * NEXP);
        float4 u = g4[0], v = g4[1];
        p[0] += c * u.x; p[1] += c * u.y; p[2] += c * u.z; p[3] += c * u.w;
        p[4] += c * v.x; p[5] += c * v.y; p[6] += c * v.z; p[7] += c * v.w;
    }
    __shared__ float red[4][NEXP];
    const int lane = t & 63, wave = t >> 6;
    #pragma unroll
    for (int e = 0; e < NEXP; ++e) {
        float v = p[e];
        v += __shfl_down(v, 32); v += __shfl_down(v, 16); v += __shfl_down(v, 8);
        v += __shfl_down(v, 4);  v += __shfl_down(v, 2);  v += __shfl_down(v, 1);
        if (lane == 0) red[wave][e] = v;
    }
    __syncthreads();
    if (t < NEXP) {
        float s = red[0][t] + red[1][t] + red[2][t] + red[3][t] + gb[t];
        gating[(size_t)b * NEXP + t] = 1.0f / (1.0f + __expf(-s));
    }
}

// ---------------------------------------------------------------------------
// Kernel 3 (fast path): m97-style GEMM. Both A (combined) and B (Wb, [o][k])
// staged via global_load_lds width-16. 128x128 tile, BK=32, 4 waves x (4x4)
// 16x16x32_bf16 frags. Epilogue: gate-scale + gated bias, atomic over experts.
// ---------------------------------------------------------------------------
__global__ __launch_bounds__(256) void moe_gemm_fast(
    const unsigned short* __restrict__ cb, const unsigned short* __restrict__ Wb,
    const float* __restrict__ gating, const float* __restrict__ eb,
    float* __restrict__ out)
{
    __shared__ unsigned short As[128 * 32];  // [m][k], 64B rows
    __shared__ unsigned short Bs[128 * 32];  // [n][k], 64B rows

    const int t = threadIdx.x;
    const int lane = t & 63, wave = t >> 6;
    const int n0 = blockIdx.x * 128;
    const int m0 = blockIdx.y * 128;
    const int e  = blockIdx.z;

    f32x4 acc[4][4];
    #pragma unroll
    for (int i = 0; i < 4; ++i)
        #pragma unroll
        for (int j = 0; j < 4; ++j) acc[i][j] = (f32x4){0.f, 0.f, 0.f, 0.f};

    // staging: row = t>>2, 16B chunk = t&3  (matches gload_lds lane order)
    const int srow = t >> 2, scg = t & 3;
    const unsigned short* ag0 = cb + (size_t)(m0 + srow) * INDIM + scg * 8;
    const unsigned short* bg0 = Wb + (size_t)e * ((size_t)ODIM * INDIM)
                                   + (size_t)(n0 + srow) * INDIM + scg * 8;
    unsigned short* al0 = As + wave * 512;
    unsigned short* al1 = As + 2048 + wave * 512;
    unsigned short* bl0 = Bs + wave * 512;
    unsigned short* bl1 = Bs + 2048 + wave * 512;

    const int fm = lane & 15, fq = lane >> 4;
    const int wn = (wave & 1) * 64;
    const int wm = (wave >> 1) * 64;

    for (int k0 = 0; k0 < INDIM; k0 += 32) {
        __syncthreads();
        gload_lds16(ag0 + k0, al0);
        gload_lds16(ag0 + (size_t)64 * INDIM + k0, al1);
        gload_lds16(bg0 + k0, bl0);
        gload_lds16(bg0 + (size_t)64 * INDIM + k0, bl1);
        __syncthreads();

        bf16x8 af[4], bfr[4];
        #pragma unroll
        for (int mi = 0; mi < 4; ++mi)
            af[mi] = *(const bf16x8*)(As + (wm + mi * 16 + fm) * 32 + fq * 8);
        #pragma unroll
        for (int ni = 0; ni < 4; ++ni)
            bfr[ni] = *(const bf16x8*)(Bs + (wn + ni * 16 + fm) * 32 + fq * 8);
        #pragma unroll
        for (int mi = 0; mi < 4; ++mi)
            #pragma unroll
            for (int ni = 0; ni < 4; ++ni)
                acc[mi][ni] = __builtin_amdgcn_mfma_f32_16x16x32_bf16(af[mi], bfr[ni], acc[mi][ni], 0, 0, 0);
    }

    #pragma unroll
    for (int mi = 0; mi < 4; ++mi) {
        const int grow = m0 + wm + mi * 16 + fq * 4;
        const float g0 = gating[(size_t)(grow + 0) * NEXP + e];
        const float g1 = gating[(size_t)(grow + 1) * NEXP + e];
        const float g2 = gating[(size_t)(grow + 2) * NEXP + e];
        const float g3 = gating[(size_t)(grow + 3) * NEXP + e];
        #pragma unroll
        for (int ni = 0; ni < 4; ++ni) {
            const int gcol = n0 + wn + ni * 16 + fm;
            const float bias = eb[(size_t)e * ODIM + gcol];
            f32x4 a = acc[mi][ni];
            unsafeAtomicAdd(out + (size_t)(grow + 0) * ODIM + gcol, g0 * (a.x + bias));
            unsafeAtomicAdd(out + (size_t)(grow + 1) * ODIM + gcol, g1 * (a.y + bias));
            unsafeAtomicAdd(out + (size_t)(grow + 2) * ODIM + gcol, g2 * (a.z + bias));
            unsafeAtomicAdd(out + (size_t)(grow + 3) * ODIM + gcol, g3 * (a.w + bias));
        }
    }
}

// ---------------------------------------------------------------------------
// Kernel 3 (fallback, round-1): in-loop fp32->bf16 W staging.
// ---------------------------------------------------------------------------
__global__ __launch_bounds__(256) void moe_gemm_slow(
    const unsigned short* __restrict__ cb, const float* __restrict__ W,
    const float* __restrict__ gating, const float* __restrict__ eb,
    float* __restrict__ out)
{
    __shared__ unsigned short As[128 * 32];
    __shared__ unsigned short Bs[128 * 32];

    const int t = threadIdx.x;
    const int lane = t & 63, wave = t >> 6;
    const int n0 = blockIdx.x * 128;
    const int m0 = blockIdx.y * 128;
    const int e  = blockIdx.z;

    f32x4 acc[4][4];
    #pragma unroll
    for (int i = 0; i < 4; ++i)
        #pragma unroll
        for (int j = 0; j < 4; ++j) acc[i][j] = (f32x4){0.f, 0.f, 0.f, 0.f};

    const int arow = t >> 2, acg = t & 3;
    const unsigned short* ag0 = cb + (size_t)(m0 + arow) * INDIM + acg * 8;
    unsigned short* al0 = As + wave * 512;
    unsigned short* al1 = As + 2048 + wave * 512;

    const int bg = t & 15;
    const int bu = t >> 4;
    const float* wg = W + (size_t)e * ((size_t)INDIM * ODIM) + (size_t)(2 * bg) * ODIM + n0 + bu * 8;
    unsigned int* bl = (unsigned int*)Bs + bg + bu * 128;

    const int fm = lane & 15, fq = lane >> 4;
    const int wn = (wave & 1) * 64;
    const int wm = (wave >> 1) * 64;

    for (int k0 = 0; k0 < INDIM; k0 += 32) {
        __syncthreads();
        gload_lds16(ag0 + k0, al0);
        gload_lds16(ag0 + (size_t)64 * INDIM + k0, al1);
        const float* wp = wg + (size_t)k0 * ODIM;
        float4 r0a = *(const float4*)(wp);
        float4 r0b = *(const float4*)(wp + 4);
        float4 r1a = *(const float4*)(wp + ODIM);
        float4 r1b = *(const float4*)(wp + ODIM + 4);
        bl[0 * 16] = pack2(r0a.x, r1a.x);
        bl[1 * 16] = pack2(r0a.y, r1a.y);
        bl[2 * 16] = pack2(r0a.z, r1a.z);
        bl[3 * 16] = pack2(r0a.w, r1a.w);
        bl[4 * 16] = pack2(r0b.x, r1b.x);
        bl[5 * 16] = pack2(r0b.y, r1b.y);
        bl[6 * 16] = pack2(r0b.z, r1b.z);
        bl[7 * 16] = pack2(r0b.w, r1b.w);
        __syncthreads();

        bf16x8 af[4], bfr[4];
        #pragma unroll
        for (int mi = 0; mi < 4; ++mi)
            af[mi] = *(const bf16x8*)(As + (wm + mi * 16 + fm) * 32 + fq * 8);
        #pragma unroll
        for (int ni = 0; ni < 4; ++ni)
            bfr[ni] = *(const bf16x8*)(Bs + (wn + ni * 16 + fm) * 32 + fq * 8);
        #pragma unroll
        for (int mi = 0; mi < 4; ++mi)
            #pragma unroll
            for (int ni = 0; ni < 4; ++ni)
                acc[mi][ni] = __builtin_amdgcn_mfma_f32_16x16x32_bf16(af[mi], bfr[ni], acc[mi][ni], 0, 0, 0);
    }

    #pragma unroll
    for (int mi = 0; mi < 4; ++mi) {
        const int grow = m0 + wm + mi * 16 + fq * 4;
        const float g0 = gating[(size_t)(grow + 0) * NEXP + e];
        const float g1 = gating[(size_t)(grow + 1) * NEXP + e];
        const float g2 = gating[(size_t)(grow + 2) * NEXP + e];
        const float g3 = gating[(size_t)(grow + 3) * NEXP + e];
        #pragma unroll
        for (int ni = 0; ni < 4; ++ni) {
            const int gcol = n0 + wn + ni * 16 + fm;
            const float bias = eb[(size_t)e * ODIM + gcol];
            f32x4 a = acc[mi][ni];
            unsafeAtomicAdd(out + (size_t)(grow + 0) * ODIM + gcol, g0 * (a.x + bias));
            unsafeAtomicAdd(out + (size_t)(grow + 1) * ODIM + gcol, g1 * (a.y + bias));
            unsafeAtomicAdd(out + (size_t)(grow + 2) * ODIM + gcol, g2 * (a.z + bias));
            unsafeAtomicAdd(out + (size_t)(grow + 3) * ODIM + gcol, g3 * (a.w + bias));
        }
    }
}

// ---------------------------------------------------------------------------
extern "C" void kernel_launch(void* const* d_in, const int* in_sizes, int n_in,
                              void* d_out, int out_size, void* d_ws, size_t ws_size,
                              hipStream_t stream) {
    const float* features    = (const float*)d_in[0];
    const float* labels      = (const float*)d_in[1];
    const float* label_embed = (const float*)d_in[2];
    const float* gate_w      = (const float*)d_in[3];
    const float* gate_b      = (const float*)d_in[4];
    const float* expert_w    = (const float*)d_in[5];
    const float* expert_b    = (const float*)d_in[6];
    float* out = (float*)d_out;

    // ws layout: Wb bf16 [8][2048][2560] | cb bf16 [1024][2560] | gating f32
    const size_t wb_bytes = (size_t)NEXP * ODIM * INDIM * 2;        // 83,886,080
    const size_t cb_bytes = (size_t)BATCH * INDIM * 2;              //  5,242,880
    const size_t gt_bytes = (size_t)BATCH * NEXP * 4;               //     32,768
    const bool fast = ws_size >= wb_bytes + cb_bytes + gt_bytes;

    hipMemsetAsync(d_out, 0, (size_t)BATCH * ODIM * sizeof(float), stream);

    if (fast) {
        unsigned short* Wb = (unsigned short*)d_ws;
        unsigned short* cb = (unsigned short*)((char*)d_ws + wb_bytes);
        float* gating = (float*)((char*)d_ws + wb_bytes + cb_bytes);
        convert_w<<<dim3(ODIM / 256, INDIM / 32, NEXP), 256, 0, stream>>>(expert_w, Wb);
        prep_kernel<<<BATCH / 4, 256, 0, stream>>>(features, labels, label_embed, cb);
        gate_kernel<<<BATCH, 256, 0, stream>>>(cb, gate_w, gate_b, gating);
        moe_gemm_fast<<<dim3(ODIM / 128, BATCH / 128, NEXP), 256, 0, stream>>>(cb, Wb, gating, expert_b, out);
    } else {
        unsigned short* cb = (unsigned short*)d_ws;
        float* gating = (float*)((char*)d_ws + cb_bytes);
        prep_kernel<<<BATCH / 4, 256, 0, stream>>>(features, labels, label_embed, cb);
        gate_kernel<<<BATCH, 256, 0, stream>>>(cb, gate_w, gate_b, gating);
        moe_gemm_slow<<<dim3(ODIM / 128, BATCH / 128, NEXP), 256, 0, stream>>>(cb, expert_w, gating, expert_b, out);
    }
}